// Round 1
// baseline (349.872 us; speedup 1.0000x reference)
//
#include <hip/hip_runtime.h>
#include <hip/hip_bf16.h>
#include <math.h>

#define B_ 2
#define S_ 2048
#define D_ 2048
#define H_ 16
#define HD_ 128
#define NT_ (B_*S_)
#define GS_ 0.1f

typedef _Float16 half8 __attribute__((__vector_size__(16)));
typedef _Float16 half4v __attribute__((__vector_size__(8)));
typedef float f32x4 __attribute__((__vector_size__(16)));

__device__ __forceinline__ void gload_lds16(const void* g, void* s) {
  __builtin_amdgcn_global_load_lds(
      (const __attribute__((address_space(1))) unsigned int*)g,
      (__attribute__((address_space(3))) unsigned int*)s, 16, 0, 0);
}

// ---------------- prep kernels ----------------

__global__ void cvt_f32_to_f16(const float* __restrict__ in, _Float16* __restrict__ out, int n4) {
  int i = blockIdx.x * blockDim.x + threadIdx.x;
  if (i >= n4) return;
  float4 v = ((const float4*)in)[i];
  half4v o = { (_Float16)v.x, (_Float16)v.y, (_Float16)v.z, (_Float16)v.w };
  ((half4v*)out)[i] = o;
}

// out[c][r] = (f16) in[r][c]   (in: R x C fp32 row-major)
__global__ void transpose_to_f16(const float* __restrict__ in, _Float16* __restrict__ out, int R, int C) {
  __shared__ float t[32][33];
  int c0 = blockIdx.x*32, r0 = blockIdx.y*32;
  int tx = threadIdx.x, ty = threadIdx.y;
#pragma unroll
  for (int j = 0; j < 32; j += 8)
    t[ty+j][tx] = in[(size_t)(r0+ty+j)*C + c0+tx];
  __syncthreads();
#pragma unroll
  for (int j = 0; j < 32; j += 8)
    out[(size_t)(c0+ty+j)*R + r0+tx] = (_Float16)t[tx][ty+j];
}

__global__ void prep_tables(const float* __restrict__ mw, float* __restrict__ cost,
                            float* __restrict__ sint, float* __restrict__ lmw) {
  int t = blockIdx.x*256 + threadIdx.x;
  if (t < S_*64) {
    int s = t >> 6, d = t & 63;
    float inv = (float)pow(10000.0, -(double)(2*d)/(double)HD_);
    float f = (float)s * inv;
    cost[t] = cosf(f);
    sint[t] = sinf(f);
  }
  if (t < B_*S_) lmw[t] = log1pf(mw[t]*GS_ + 1e-8f);
}

// ---------------- GEMM: C[M,N] = A[M,K] * Bt[N,K]^T ----------------
// 128x128 tile, BK=64, 4 waves (2x2), 16x16x32 fp16 MFMA.
// LDS rows are 128B (8 x 16B chunks); chunk index XOR-swizzled with (row&7),
// applied on the *global source* address so global_load_lds (linear dest) works.

template<bool F32OUT>
__global__ __launch_bounds__(256) void gemm_f16(
    const _Float16* __restrict__ A, const _Float16* __restrict__ Bt,
    void* __restrict__ Cout, const float* __restrict__ bias,
    int M, int N, int K)
{
  __shared__ __align__(16) _Float16 As[128*64];
  __shared__ __align__(16) _Float16 Bs[128*64];
  int n0 = blockIdx.x*128, m0 = blockIdx.y*128;
  int tid = threadIdx.x;
  int w = tid >> 6, l = tid & 63;
  int lhi = l >> 4, llo = l & 15;
  int wr = w >> 1, wc = w & 1;
  const f32x4 fz = {0.f,0.f,0.f,0.f};
  f32x4 acc[4][4];
#pragma unroll
  for (int i = 0; i < 4; ++i)
#pragma unroll
    for (int j = 0; j < 4; ++j) acc[i][j] = fz;

  for (int kt = 0; kt < K; kt += 64) {
#pragma unroll
    for (int i = 0; i < 4; ++i) {
      int sid = i*256 + tid;          // 16B slot id, 1024 slots = 16KB
      int row = sid >> 3;
      int c   = (sid & 7) ^ (row & 7);
      gload_lds16(A  + (size_t)(m0+row)*K + kt + c*8, (char*)As + (size_t)(i*256 + w*64)*16);
      gload_lds16(Bt + (size_t)(n0+row)*K + kt + c*8, (char*)Bs + (size_t)(i*256 + w*64)*16);
    }
    __syncthreads();
#pragma unroll
    for (int kk = 0; kk < 2; ++kk) {
      half8 a[4], b[4];
#pragma unroll
      for (int mi = 0; mi < 4; ++mi) {
        int row = wr*64 + mi*16 + llo;
        int ch = (kk*4 + lhi) ^ (row & 7);
        a[mi] = *(const half8*)((const char*)As + row*128 + ch*16);
      }
#pragma unroll
      for (int ni = 0; ni < 4; ++ni) {
        int row = wc*64 + ni*16 + llo;
        int ch = (kk*4 + lhi) ^ (row & 7);
        b[ni] = *(const half8*)((const char*)Bs + row*128 + ch*16);
      }
#pragma unroll
      for (int mi = 0; mi < 4; ++mi)
#pragma unroll
        for (int ni = 0; ni < 4; ++ni)
          acc[mi][ni] = __builtin_amdgcn_mfma_f32_16x16x32_f16(a[mi], b[ni], acc[mi][ni], 0, 0, 0);
    }
    __syncthreads();
  }
#pragma unroll
  for (int mi = 0; mi < 4; ++mi)
#pragma unroll
    for (int ni = 0; ni < 4; ++ni)
#pragma unroll
      for (int r = 0; r < 4; ++r) {
        int row = m0 + wr*64 + mi*16 + lhi*4 + r;
        int col = n0 + wc*64 + ni*16 + llo;
        if constexpr (F32OUT)
          ((float*)Cout)[(size_t)row*N + col] = acc[mi][ni][r] + bias[col];
        else
          ((_Float16*)Cout)[(size_t)row*N + col] = (_Float16)acc[mi][ni][r];
      }
}

// ---------------- RoPE + head reorder for Q,K ----------------
// qkv: [token][3*D] (q|k|v). Writes Qr/Kr as [b,h,s,d] fp16.
__global__ void rope_qk(const _Float16* __restrict__ qkv, const float* __restrict__ cost,
                        const float* __restrict__ sint, _Float16* __restrict__ Qr,
                        _Float16* __restrict__ Kr) {
  int token = blockIdx.x;
  int b = token >> 11, s = token & (S_-1);
  int t = threadIdx.x;
  int isk = t >> 7, u = t & 127;
  int hh = u >> 3, dd0 = (u & 7)*8;
  const _Float16* src = qkv + (size_t)token*(3*D_) + (size_t)isk*D_ + hh*128;
  half8 a  = *(const half8*)(src + dd0);
  half8 bb = *(const half8*)(src + 64 + dd0);
  half8 lo, hi;
#pragma unroll
  for (int j = 0; j < 8; ++j) {
    float c  = cost[s*64 + dd0 + j];
    float sn = sint[s*64 + dd0 + j];
    float x1 = (float)a[j], x2 = (float)bb[j];
    lo[j] = (_Float16)(x1*c - x2*sn);
    hi[j] = (_Float16)(x2*c + x1*sn);
  }
  _Float16* dst = (isk ? Kr : Qr) + ((size_t)(b*H_ + hh)*S_ + s)*HD_;
  *(half8*)(dst + dd0) = lo;
  *(half8*)(dst + 64 + dd0) = hi;
}

// ---------------- V transpose: qkv v-part -> Vt[b,h,d,s] ----------------
__global__ void v_transpose(const _Float16* __restrict__ qkv, _Float16* __restrict__ Vt) {
  __shared__ _Float16 tile[64][33];
  int st = blockIdx.x*64;
  int dt = blockIdx.y*32;
  int bh = blockIdx.z;
  int b = bh >> 4, h = bh & 15;
  int t = threadIdx.x;
  int s = t >> 2, dc = (t & 3)*8;
  half8 v = *(const half8*)(qkv + (size_t)(b*S_ + st + s)*(3*D_) + 2*D_ + h*128 + dt + dc);
#pragma unroll
  for (int j = 0; j < 8; ++j) tile[s][dc+j] = v[j];
  __syncthreads();
  int d = t >> 3, sc = (t & 7)*8;
  half8 o;
#pragma unroll
  for (int j = 0; j < 8; ++j) o[j] = tile[sc+j][d];
  *(half8*)(Vt + ((size_t)bh*HD_ + dt + d)*S_ + st + sc) = o;
}

// ---------------- flash attention ----------------
// 4 waves x 16 q-rows = 64-row q-tile, KVBLK=64. K/V staged via swizzled
// global_load_lds; P through per-wave swizzled LDS buffer.
__global__ __launch_bounds__(256) void attn_kernel(
    const _Float16* __restrict__ Qr, const _Float16* __restrict__ Kr,
    const _Float16* __restrict__ Vt, const float* __restrict__ policy,
    const float* __restrict__ lmw, _Float16* __restrict__ Ob)
{
  __shared__ __align__(16) _Float16 Kl[64*128];   // [key][d], chunk^=(key&7)
  __shared__ __align__(16) _Float16 Vl[128*64];   // [d][key], chunk^=(d&7)
  __shared__ __align__(16) _Float16 Pl[4][16*64]; // per-wave [q][key], chunk^=(q&7)
  int bx = blockIdx.x;
  int qt = (S_/64) - 1 - (bx / (B_*H_));   // heavy tiles first
  int rem = bx % (B_*H_);
  int h = rem >> 1;
  int b = rem & 1;                          // b fastest -> policy L3 reuse
  int bh = b*H_ + h;
  const _Float16* Qb = Qr + (size_t)bh*S_*HD_;
  const _Float16* Kb = Kr + (size_t)bh*S_*HD_;
  const _Float16* Vb = Vt + (size_t)bh*HD_*S_;
  const float* pol = policy + (size_t)h*S_*S_;
  int tid = threadIdx.x;
  int w = tid >> 6, l = tid & 63;
  int lhi = l >> 4, llo = l & 15;
  int q0 = qt*64 + w*16;

  half8 qf[4];
#pragma unroll
  for (int c = 0; c < 4; ++c)
    qf[c] = *(const half8*)(Qb + (size_t)(q0+llo)*HD_ + c*32 + lhi*8);

  const f32x4 fz = {0.f,0.f,0.f,0.f};
  f32x4 outacc[8];
#pragma unroll
  for (int i = 0; i < 8; ++i) outacc[i] = fz;
  float m_[4], l_[4];
#pragma unroll
  for (int r = 0; r < 4; ++r) { m_[r] = -INFINITY; l_[r] = 0.f; }

  const float scale = 0.08838834764831845f;  // 1/sqrt(128)
  _Float16* Pw = &Pl[w][0];

  for (int t = 0; t <= qt; ++t) {
    int kv0 = t*64;
#pragma unroll
    for (int i = 0; i < 4; ++i) {
      int sid = i*256 + tid;
      int key = sid >> 4;
      int ck = (sid & 15) ^ (key & 7);
      gload_lds16(Kb + (size_t)(kv0+key)*HD_ + ck*8, (char*)Kl + (size_t)(i*256 + w*64)*16);
      int dv = sid >> 3;
      int cv = (sid & 7) ^ (dv & 7);
      gload_lds16(Vb + (size_t)dv*S_ + kv0 + cv*8, (char*)Vl + (size_t)(i*256 + w*64)*16);
    }
    __syncthreads();

    // S = Q K^T
    f32x4 sacc[4];
#pragma unroll
    for (int kf = 0; kf < 4; ++kf) sacc[kf] = fz;
#pragma unroll
    for (int kf = 0; kf < 4; ++kf) {
      int key = kf*16 + llo;
#pragma unroll
      for (int c = 0; c < 4; ++c) {
        int ch = (c*4 + lhi) ^ (key & 7);
        half8 kfr = *(const half8*)((const char*)Kl + key*256 + ch*16);
        sacc[kf] = __builtin_amdgcn_mfma_f32_16x16x32_f16(qf[c], kfr, sacc[kf], 0, 0, 0);
      }
    }

    // bias + causal mask
    bool diag = (t == qt);
    float lm[4];
#pragma unroll
    for (int kf = 0; kf < 4; ++kf) lm[kf] = lmw[b*S_ + kv0 + kf*16 + llo];
    float pv[4][4];
#pragma unroll
    for (int kf = 0; kf < 4; ++kf) {
      int gk = kv0 + kf*16 + llo;
#pragma unroll
      for (int r = 0; r < 4; ++r) {
        int gq = q0 + lhi*4 + r;
        float v = sacc[kf][r]*scale + pol[(size_t)gq*S_ + gk]*GS_ + lm[kf];
        if (diag && gk > gq) v = -1e9f;
        pv[kf][r] = v;
      }
    }
    // online softmax (rows live on 16-lane groups)
    float fct[4];
#pragma unroll
    for (int r = 0; r < 4; ++r) {
      float mx = fmaxf(fmaxf(pv[0][r], pv[1][r]), fmaxf(pv[2][r], pv[3][r]));
#pragma unroll
      for (int s = 8; s > 0; s >>= 1) mx = fmaxf(mx, __shfl_xor(mx, s, 16));
      float mnew = fmaxf(m_[r], mx);
      fct[r] = __expf(m_[r] - mnew);
      m_[r] = mnew;
    }
    float rsum[4] = {0.f,0.f,0.f,0.f};
#pragma unroll
    for (int kf = 0; kf < 4; ++kf)
#pragma unroll
      for (int r = 0; r < 4; ++r) {
        float p = __expf(pv[kf][r] - m_[r]);
        pv[kf][r] = p;
        rsum[r] += p;
      }
#pragma unroll
    for (int r = 0; r < 4; ++r) {
      float rs = rsum[r];
#pragma unroll
      for (int s = 8; s > 0; s >>= 1) rs += __shfl_xor(rs, s, 16);
      l_[r] = l_[r]*fct[r] + rs;
    }
#pragma unroll
    for (int i = 0; i < 8; ++i) {
      f32x4 o = outacc[i];
      o[0] *= fct[0]; o[1] *= fct[1]; o[2] *= fct[2]; o[3] *= fct[3];
      outacc[i] = o;
    }
    // P -> per-wave LDS (swizzled), then PV
#pragma unroll
    for (int kf = 0; kf < 4; ++kf)
#pragma unroll
      for (int r = 0; r < 4; ++r) {
        int pq = lhi*4 + r, pk = kf*16 + llo;
        int byte = (pq*128 + pk*2) ^ ((pq & 7) << 4);
        *(_Float16*)((char*)Pw + byte) = (_Float16)pv[kf][r];
      }
#pragma unroll
    for (int kc = 0; kc < 2; ++kc) {
      int ch = (kc*4 + lhi) ^ (llo & 7);
      half8 pa = *(const half8*)((const char*)Pw + llo*128 + ch*16);
#pragma unroll
      for (int db = 0; db < 8; ++db) {
        int d = db*16 + llo;
        int chv = (kc*4 + lhi) ^ (d & 7);
        half8 vb = *(const half8*)((const char*)Vl + d*128 + chv*16);
        outacc[db] = __builtin_amdgcn_mfma_f32_16x16x32_f16(pa, vb, outacc[db], 0, 0, 0);
      }
    }
    __syncthreads();
  }
#pragma unroll
  for (int db = 0; db < 8; ++db)
#pragma unroll
    for (int r = 0; r < 4; ++r) {
      int gq = q0 + lhi*4 + r;
      float o = outacc[db][r] / l_[r];
      Ob[((size_t)b*S_ + gq)*D_ + h*HD_ + db*16 + llo] = (_Float16)o;
    }
}

// ---------------- launch ----------------

extern "C" void kernel_launch(void* const* d_in, const int* in_sizes, int n_in,
                              void* d_out, int out_size, void* d_ws, size_t ws_size,
                              hipStream_t stream) {
  const float* x   = (const float*)d_in[0];
  const float* Wq  = (const float*)d_in[1];
  const float* Wk  = (const float*)d_in[2];
  const float* Wv  = (const float*)d_in[3];
  const float* Wo  = (const float*)d_in[4];
  const float* bo  = (const float*)d_in[5];
  const float* pol = (const float*)d_in[6];
  const float* mw  = (const float*)d_in[7];
  float* out = (float*)d_out;

  char* p = (char*)d_ws;
  auto take = [&](size_t bytes) { char* r = p; p += (bytes + 255) & ~(size_t)255; return r; };
  _Float16* xb   = (_Float16*)take((size_t)NT_*D_*2);
  _Float16* Wt   = (_Float16*)take((size_t)3*D_*D_*2);   // [Wq^T;Wk^T;Wv^T] as [n][k]
  _Float16* Wot  = (_Float16*)take((size_t)D_*D_*2);
  _Float16* qkv  = (_Float16*)take((size_t)NT_*3*D_*2);
  _Float16* Qr   = (_Float16*)take((size_t)B_*H_*S_*HD_*2);
  _Float16* Kr   = (_Float16*)take((size_t)B_*H_*S_*HD_*2);
  _Float16* Vtb  = (_Float16*)take((size_t)B_*H_*S_*HD_*2);
  _Float16* Ob   = (_Float16*)take((size_t)NT_*D_*2);
  float* cost = (float*)take((size_t)S_*64*4);
  float* sint = (float*)take((size_t)S_*64*4);
  float* lmwb = (float*)take((size_t)B_*S_*4);

  cvt_f32_to_f16<<<(NT_*D_/4 + 255)/256, 256, 0, stream>>>(x, xb, NT_*D_/4);
  transpose_to_f16<<<dim3(64,64), dim3(32,8), 0, stream>>>(Wq, Wt,                    D_, D_);
  transpose_to_f16<<<dim3(64,64), dim3(32,8), 0, stream>>>(Wk, Wt +   (size_t)D_*D_,  D_, D_);
  transpose_to_f16<<<dim3(64,64), dim3(32,8), 0, stream>>>(Wv, Wt + 2*(size_t)D_*D_,  D_, D_);
  transpose_to_f16<<<dim3(64,64), dim3(32,8), 0, stream>>>(Wo, Wot, D_, D_);
  prep_tables<<<512, 256, 0, stream>>>(mw, cost, sint, lmwb);

  gemm_f16<false><<<dim3(3*D_/128, NT_/128), 256, 0, stream>>>(xb, Wt, qkv, nullptr, NT_, 3*D_, D_);
  rope_qk<<<NT_, 256, 0, stream>>>(qkv, cost, sint, Qr, Kr);
  v_transpose<<<dim3(S_/64, HD_/32, B_*H_), 256, 0, stream>>>(qkv, Vtb);
  attn_kernel<<<B_*H_*(S_/64), 256, 0, stream>>>(Qr, Kr, Vtb, pol, lmwb, Ob);
  gemm_f16<true><<<dim3(D_/128, NT_/128), 256, 0, stream>>>(Ob, Wot, out, bo, NT_, D_, D_);
}